// Round 1
// baseline (369.481 us; speedup 1.0000x reference)
//
#include <hip/hip_runtime.h>
#include <hip/hip_bf16.h>
#include <stdint.h>

#define BATCH  16384
#define GAMMA  0.01f

using f32x4  = __attribute__((ext_vector_type(4))) float;
using bf16x8 = __attribute__((ext_vector_type(8))) __bf16;

// ---------- helpers ----------
__device__ __forceinline__ unsigned short f2bf(float f) {
  unsigned int u = __float_as_uint(f);
  unsigned int r = (u + 0x7fffu + ((u >> 16) & 1u)) >> 16;  // RNE
  return (unsigned short)r;
}
__device__ __forceinline__ float bf2f(unsigned short u) {
  return __uint_as_float(((unsigned int)u) << 16);
}
__device__ __forceinline__ float sigmoidf_(float x) {
  return 1.0f / (1.0f + __expf(-x));
}
__device__ __forceinline__ float tanhf_(float x) {
  float e = __expf(2.0f * x);
  return (e - 1.0f) / (e + 1.0f);
}
__device__ __forceinline__ void gload_lds16(const void* gsrc, void* ldst) {
  __builtin_amdgcn_global_load_lds(
      (const __attribute__((address_space(1))) void*)gsrc,
      (__attribute__((address_space(3))) void*)ldst, 16, 0, 0);
}

// ---------- GEMM: C[M][N] = X[M][K] @ W[N][K]^T, all bf16, C bf16 ----------
// m97 structure: 128x128 tile, BK=32, 256 threads (4 waves, 2x2), 4x4 frags/wave.
__global__ __launch_bounds__(256, 2) void gemm_bt(
    const unsigned short* __restrict__ X, const unsigned short* __restrict__ W,
    unsigned short* __restrict__ C, int lda, int K, int N) {
  __shared__ unsigned short As[128 * 32];
  __shared__ unsigned short Bs[128 * 32];

  const int tiles_n = N >> 7;
  const int brow = blockIdx.x / tiles_n;
  const int bcol = blockIdx.x % tiles_n;
  const int t    = threadIdx.x;
  const int lane = t & 63;
  const int wave = t >> 6;
  const int wr = (wave >> 1) * 64;   // wave row offset in tile
  const int wc = (wave & 1) * 64;    // wave col offset in tile
  const int lr = lane & 15;
  const int kg = (lane >> 4) * 8;

  // staging: thread t loads 8 bf16 (16B); round j covers rows j*64..j*64+63
  const int srow = t >> 2;           // 0..63
  const int scol = (t & 3) * 8;      // 0,8,16,24

  const unsigned short* Ag = X + (size_t)(brow * 128 + srow) * lda + scol;
  const unsigned short* Bg = W + (size_t)(bcol * 128 + srow) * K + scol;
  unsigned short* AsW0 = As + wave * 512;          // wave-uniform LDS dest bases
  unsigned short* AsW1 = As + 2048 + wave * 512;
  unsigned short* BsW0 = Bs + wave * 512;
  unsigned short* BsW1 = Bs + 2048 + wave * 512;

  f32x4 acc[4][4] = {};

  for (int k0 = 0; k0 < K; k0 += 32) {
    gload_lds16(Ag + k0, AsW0);
    gload_lds16(Ag + (size_t)64 * lda + k0, AsW1);
    gload_lds16(Bg + k0, BsW0);
    gload_lds16(Bg + (size_t)64 * K + k0, BsW1);
    __syncthreads();  // drains vmcnt -> staged data visible

    bf16x8 af[4], bfr[4];
#pragma unroll
    for (int i = 0; i < 4; ++i)
      af[i] = *(const bf16x8*)(As + (wr + i * 16 + lr) * 32 + kg);
#pragma unroll
    for (int i = 0; i < 4; ++i)
      bfr[i] = *(const bf16x8*)(Bs + (wc + i * 16 + lr) * 32 + kg);
#pragma unroll
    for (int i = 0; i < 4; ++i)
#pragma unroll
      for (int j = 0; j < 4; ++j)
        acc[i][j] = __builtin_amdgcn_mfma_f32_16x16x32_bf16(af[i], bfr[j], acc[i][j], 0, 0, 0);
    __syncthreads();  // all waves done reading before next stage overwrites
  }

  // C/D layout: col = lane&15, row = (lane>>4)*4 + reg  [m89/m91 verified]
  const int rbase = brow * 128 + wr + (lane >> 4) * 4;
  const int cbase = bcol * 128 + wc + lr;
#pragma unroll
  for (int i = 0; i < 4; ++i)
#pragma unroll
    for (int j = 0; j < 4; ++j)
#pragma unroll
      for (int q = 0; q < 4; ++q)
        C[(size_t)(rbase + i * 16 + q) * N + cbase + j * 16] = f2bf(acc[i][j][q]);
}

// ---------- prep kernels ----------
// Xcat[m][0:1024] = bf16(x[m]), Xcat[m][1024:2048] = bf16(h[m])
__global__ void prep_x_kernel(const float* __restrict__ x, const float* __restrict__ h,
                              unsigned short* __restrict__ Xcat) {
  const int total4 = BATCH * 2048 / 4;
  for (int i = blockIdx.x * blockDim.x + threadIdx.x; i < total4; i += gridDim.x * blockDim.x) {
    const int e = i * 4;
    const int m = e >> 11;
    const int c = e & 2047;
    float4 v = (c < 1024) ? *(const float4*)(x + (size_t)m * 1024 + c)
                          : *(const float4*)(h + (size_t)m * 1024 + (c - 1024));
    ushort4 o;
    o.x = f2bf(v.x); o.y = f2bf(v.y); o.z = f2bf(v.z); o.w = f2bf(v.w);
    *(ushort4*)(Xcat + e) = o;
  }
}

// Wcat rows 0..1023 = [W_z | U_z], rows 1024..2047 = [W_r | U_r]
__global__ void prep_wcat_kernel(const float* __restrict__ Wz, const float* __restrict__ Uz,
                                 const float* __restrict__ Wr, const float* __restrict__ Ur,
                                 unsigned short* __restrict__ Wcat) {
  const int total4 = 2048 * 2048 / 4;
  for (int i = blockIdx.x * blockDim.x + threadIdx.x; i < total4; i += gridDim.x * blockDim.x) {
    const int e = i * 4;
    const int n = e >> 11;
    const int c = e & 2047;
    const float* src;
    if (n < 1024) src = (c < 1024) ? (Wz + (size_t)n * 1024 + c) : (Uz + (size_t)n * 1024 + c - 1024);
    else          src = (c < 1024) ? (Wr + (size_t)(n - 1024) * 1024 + c) : (Ur + (size_t)(n - 1024) * 1024 + c - 1024);
    float4 v = *(const float4*)src;
    ushort4 o;
    o.x = f2bf(v.x); o.y = f2bf(v.y); o.z = f2bf(v.z); o.w = f2bf(v.w);
    *(ushort4*)(Wcat + e) = o;
  }
}

__global__ void cast_f2b_kernel(const float* __restrict__ src, unsigned short* __restrict__ dst,
                                int total4) {
  for (int i = blockIdx.x * blockDim.x + threadIdx.x; i < total4; i += gridDim.x * blockDim.x) {
    const int e = i * 4;
    float4 v = *(const float4*)(src + e);
    ushort4 o;
    o.x = f2bf(v.x); o.y = f2bf(v.y); o.z = f2bf(v.z); o.w = f2bf(v.w);
    *(ushort4*)(dst + e) = o;
  }
}

// A = W_h - W_h^T - gamma*I  (bf16)
__global__ void prep_A_kernel(const float* __restrict__ Wh, unsigned short* __restrict__ Abf) {
  const int total4 = 1024 * 1024 / 4;
  for (int i = blockIdx.x * blockDim.x + threadIdx.x; i < total4; i += gridDim.x * blockDim.x) {
    const int e = i * 4;
    const int r = e >> 10;
    const int c = e & 1023;
    float4 v = *(const float4*)(Wh + (size_t)r * 1024 + c);
    float t0 = Wh[(size_t)(c + 0) * 1024 + r];
    float t1 = Wh[(size_t)(c + 1) * 1024 + r];
    float t2 = Wh[(size_t)(c + 2) * 1024 + r];
    float t3 = Wh[(size_t)(c + 3) * 1024 + r];
    ushort4 o;
    o.x = f2bf(v.x - t0 - ((r == c + 0) ? GAMMA : 0.0f));
    o.y = f2bf(v.y - t1 - ((r == c + 1) ? GAMMA : 0.0f));
    o.z = f2bf(v.z - t2 - ((r == c + 2) ? GAMMA : 0.0f));
    o.w = f2bf(v.w - t3 - ((r == c + 3) ? GAMMA : 0.0f));
    *(ushort4*)(Abf + e) = o;
  }
}

// hr = bf16( sigmoid(r_pre + b_r) * h_prev )
__global__ void phase3_kernel(const unsigned short* __restrict__ ZR, const float* __restrict__ br,
                              const float* __restrict__ h, unsigned short* __restrict__ hr) {
  const int total4 = BATCH * 1024 / 4;
  for (int i = blockIdx.x * blockDim.x + threadIdx.x; i < total4; i += gridDim.x * blockDim.x) {
    const int e = i * 4;
    const int m = e >> 10;
    const int n = e & 1023;
    ushort4 rp = *(const ushort4*)(ZR + (size_t)m * 2048 + 1024 + n);
    float4 b  = *(const float4*)(br + n);
    float4 hv = *(const float4*)(h + e);
    ushort4 o;
    o.x = f2bf(sigmoidf_(bf2f(rp.x) + b.x) * hv.x);
    o.y = f2bf(sigmoidf_(bf2f(rp.y) + b.y) * hv.y);
    o.z = f2bf(sigmoidf_(bf2f(rp.z) + b.z) * hv.z);
    o.w = f2bf(sigmoidf_(bf2f(rp.w) + b.w) * hv.w);
    *(ushort4*)(hr + e) = o;
  }
}

// h_new = h + eps * sigmoid(z_pre+b_z) * tanh(v_pre + b_h + hA)
__global__ void phase5_kernel(const unsigned short* __restrict__ ZR,
                              const unsigned short* __restrict__ Vpre,
                              const unsigned short* __restrict__ hA,
                              const float* __restrict__ bz, const float* __restrict__ bh,
                              const float* __restrict__ h, const float* __restrict__ eps_p,
                              float* __restrict__ out) {
  const float eps = eps_p[0];
  const int total4 = BATCH * 1024 / 4;
  for (int i = blockIdx.x * blockDim.x + threadIdx.x; i < total4; i += gridDim.x * blockDim.x) {
    const int e = i * 4;
    const int m = e >> 10;
    const int n = e & 1023;
    ushort4 zp = *(const ushort4*)(ZR + (size_t)m * 2048 + n);
    ushort4 vp = *(const ushort4*)(Vpre + e);
    ushort4 ha = *(const ushort4*)(hA + e);
    float4 bzv = *(const float4*)(bz + n);
    float4 bhv = *(const float4*)(bh + n);
    float4 hv  = *(const float4*)(h + e);
    float4 o;
    o.x = hv.x + eps * sigmoidf_(bf2f(zp.x) + bzv.x) * tanhf_(bf2f(vp.x) + bhv.x + bf2f(ha.x));
    o.y = hv.y + eps * sigmoidf_(bf2f(zp.y) + bzv.y) * tanhf_(bf2f(vp.y) + bhv.y + bf2f(ha.y));
    o.z = hv.z + eps * sigmoidf_(bf2f(zp.z) + bzv.z) * tanhf_(bf2f(vp.z) + bhv.z + bf2f(ha.z));
    o.w = hv.w + eps * sigmoidf_(bf2f(zp.w) + bzv.w) * tanhf_(bf2f(vp.w) + bhv.w + bf2f(ha.w));
    *(float4*)(out + e) = o;
  }
}

// ---------- launch ----------
extern "C" void kernel_launch(void* const* d_in, const int* in_sizes, int n_in,
                              void* d_out, int out_size, void* d_ws, size_t ws_size,
                              hipStream_t stream) {
  const float* x   = (const float*)d_in[0];
  const float* h   = (const float*)d_in[1];
  const float* Wz  = (const float*)d_in[2];
  const float* bz  = (const float*)d_in[3];
  const float* Uz  = (const float*)d_in[4];
  const float* Wr  = (const float*)d_in[5];
  const float* br  = (const float*)d_in[6];
  const float* Ur  = (const float*)d_in[7];
  const float* Vh  = (const float*)d_in[8];
  const float* bh  = (const float*)d_in[9];
  const float* Wh  = (const float*)d_in[10];
  const float* eps = (const float*)d_in[11];
  float* out = (float*)d_out;

  char* ws = (char*)d_ws;
  size_t off = 0;
  unsigned short* Xcat = (unsigned short*)(ws + off); off += (size_t)BATCH * 2048 * 2;  // 67.1MB
  unsigned short* Wcat = (unsigned short*)(ws + off); off += (size_t)2048 * 2048 * 2;   //  8.4MB
  unsigned short* Vhb  = (unsigned short*)(ws + off); off += (size_t)1024 * 1024 * 2;   //  2.1MB
  unsigned short* Abf  = (unsigned short*)(ws + off); off += (size_t)1024 * 1024 * 2;   //  2.1MB
  unsigned short* ZR   = (unsigned short*)(ws + off); off += (size_t)BATCH * 2048 * 2;  // 67.1MB
  unsigned short* Vpre = (unsigned short*)(ws + off); off += (size_t)BATCH * 1024 * 2;  // 33.6MB
  // hr / hA reuse the Xcat region (Xcat is dead after GEMM2)
  unsigned short* hr = Xcat;
  unsigned short* hA = Xcat + (size_t)BATCH * 1024;

  dim3 blk(256);
  prep_x_kernel<<<2048, blk, 0, stream>>>(x, h, Xcat);
  prep_wcat_kernel<<<1024, blk, 0, stream>>>(Wz, Uz, Wr, Ur, Wcat);
  cast_f2b_kernel<<<256, blk, 0, stream>>>(Vh, Vhb, 1024 * 1024 / 4);
  prep_A_kernel<<<256, blk, 0, stream>>>(Wh, Abf);

  // GEMM1: ZR[16384][2048] = Xcat @ Wcat^T   (z_pre | r_pre)
  gemm_bt<<<(BATCH / 128) * (2048 / 128), blk, 0, stream>>>(Xcat, Wcat, ZR, 2048, 2048, 2048);
  // GEMM2: Vpre = x @ Vh^T  (x = first half of Xcat rows, lda=2048)
  gemm_bt<<<(BATCH / 128) * (1024 / 128), blk, 0, stream>>>(Xcat, Vhb, Vpre, 2048, 1024, 1024);
  // r, hr
  phase3_kernel<<<2048, blk, 0, stream>>>(ZR, br, h, hr);
  // GEMM3: hA = hr @ A^T
  gemm_bt<<<(BATCH / 128) * (1024 / 128), blk, 0, stream>>>(hr, Abf, hA, 1024, 1024, 1024);
  // final combine
  phase5_kernel<<<2048, blk, 0, stream>>>(ZR, Vpre, hA, bz, bh, h, eps, out);
}

// Round 2
// 313.584 us; speedup vs baseline: 1.1783x; 1.1783x over previous
//
#include <hip/hip_runtime.h>
#include <hip/hip_bf16.h>
#include <stdint.h>

#define BATCH  16384
#define GAMMA  0.01f

using f32x4  = __attribute__((ext_vector_type(4))) float;
using bf16x8 = __attribute__((ext_vector_type(8))) __bf16;

#define MFMA16(a, b, c) __builtin_amdgcn_mfma_f32_16x16x32_bf16((a), (b), (c), 0, 0, 0)
#define BAR() asm volatile("s_barrier" ::: "memory")

// ---------- helpers ----------
__device__ __forceinline__ unsigned short f2bf(float f) {
  unsigned int u = __float_as_uint(f);
  unsigned int r = (u + 0x7fffu + ((u >> 16) & 1u)) >> 16;  // RNE
  return (unsigned short)r;
}
__device__ __forceinline__ float bf2f(unsigned short u) {
  return __uint_as_float(((unsigned int)u) << 16);
}
__device__ __forceinline__ float sigmoidf_(float x) {
  return 1.0f / (1.0f + __expf(-x));
}
__device__ __forceinline__ float tanhf_(float x) {
  float e = __expf(2.0f * x);
  return (e - 1.0f) / (e + 1.0f);
}
__device__ __forceinline__ void gload_lds16(const void* gsrc, void* ldst) {
  __builtin_amdgcn_global_load_lds(
      (const __attribute__((address_space(1))) void*)gsrc,
      (__attribute__((address_space(3))) void*)ldst, 16, 0, 0);
}

// ---------- 256x256 8-phase GEMM: C[M][N] = X[M][K] @ W[N][K]^T (bf16) ----------
// BM=BN=256, BK=64, 512 threads = 8 waves (2M x 4N), wave tile 128x64.
// LDS: 2 x (256x64) A + 2 x (256x64) B = 128 KiB, double-buffered.
// Per K-tile: 4 phases (quadrants Q0..Q3 of the wave tile, 16 MFMA each).
// All ds_reads of buf c happen in P1-P3 -> buf c free at P4 (post-P3 barrier).
// Staging: P1/P2/P3 stage tile T+1 halves (buf c^1), P4 stages tile T+2's
// first half into buf c. Counted vmcnt(2) at P4 (only T+2's half in flight).
// LDS swizzle: short_idx ^= (row&7)<<3 applied on read AND on pre-swizzled
// global source granule (global_load_lds writes linearly) -> 2-way conflicts.
__global__ __launch_bounds__(512, 2) void gemm256(
    const unsigned short* __restrict__ X, const unsigned short* __restrict__ W,
    unsigned short* __restrict__ C, int lda, int K, int N) {
  __shared__ unsigned short As[2 * 16384];
  __shared__ unsigned short Bs[2 * 16384];

  // XCD-aware bijective swizzle (grid % 8 == 0 for all our launches)
  const int qq  = gridDim.x >> 3;
  const int swz = (blockIdx.x & 7) * qq + (blockIdx.x >> 3);
  const int tiles_n = N >> 8;
  const int brow = swz / tiles_n;
  const int bcol = swz % tiles_n;

  const int t    = threadIdx.x;
  const int lane = t & 63;
  const int wave = t >> 6;
  const int wm   = wave >> 2;     // 0..1
  const int wn   = wave & 3;      // 0..3
  const int lr   = lane & 15;
  const int kq8  = (lane >> 4) * 8;
  const int sx   = (lr & 7) << 3;           // read-side swizzle (shorts)
  const int koff0 = kq8 ^ sx;               // k-slice 0 offset (swizzled)
  const int koff1 = (32 + kq8) ^ sx;        // k-slice 1 offset (swizzled)
  const int aBase = (wm * 128 + lr) * 64;
  const int bBase = (wn * 64 + lr) * 64;

  // staging: thread t covers row (t>>3), 16B granule (t&7); source granule is
  // pre-swizzled so linear LDS + swizzled read agree.
  const int srow = t >> 3;                  // 0..63
  const int sg   = (t & 7) ^ (srow & 7);
  const unsigned short* aSrc = X + (size_t)(brow * 256 + srow) * lda + sg * 8;
  const unsigned short* bSrc = W + (size_t)(bcol * 256 + srow) * K + sg * 8;
  const int wofs = wave * 512;              // wave-uniform LDS dest base part

  auto STAGE_A = [&](int buf, int h, int k0) {
    gload_lds16(aSrc + (size_t)(h * 128) * lda + k0,
                As + buf * 16384 + (h * 128) * 64 + wofs);
    gload_lds16(aSrc + (size_t)(h * 128 + 64) * lda + k0,
                As + buf * 16384 + (h * 128 + 64) * 64 + wofs);
  };
  auto STAGE_B = [&](int buf, int h, int k0) {
    gload_lds16(bSrc + (size_t)(h * 128) * K + k0,
                Bs + buf * 16384 + (h * 128) * 64 + wofs);
    gload_lds16(bSrc + (size_t)(h * 128 + 64) * K + k0,
                Bs + buf * 16384 + (h * 128 + 64) * 64 + wofs);
  };

  f32x4 acc[8][4] = {};
  bf16x8 aR[4][2], bR[4][2];

  const int nt = K >> 6;  // assumes nt >= 2 (K >= 128)

  // ---- prologue: tile 0 fully + tile 1 first half; leave tile1-h0 in flight
  STAGE_A(0, 0, 0); STAGE_A(0, 1, 0); STAGE_B(0, 0, 0); STAGE_B(0, 1, 0);
  STAGE_A(1, 0, 64);
  asm volatile("s_waitcnt vmcnt(2)" ::: "memory");
  BAR();

  for (int T = 0; T < nt; ++T) {
    const int c  = T & 1;
    const int cn = c ^ 1;
    const int k0n = (T + 1) << 6;
    const unsigned short* Ac = As + c * 16384;
    const unsigned short* Bc = Bs + c * 16384;

    // ---- P1: read A i0-3 + B j0-1; stage T+1 A-h1; compute Q0
#pragma unroll
    for (int i = 0; i < 4; ++i) {
      aR[i][0] = *(const bf16x8*)(Ac + aBase + i * 1024 + koff0);
      aR[i][1] = *(const bf16x8*)(Ac + aBase + i * 1024 + koff1);
    }
#pragma unroll
    for (int j = 0; j < 2; ++j) {
      bR[j][0] = *(const bf16x8*)(Bc + bBase + j * 1024 + koff0);
      bR[j][1] = *(const bf16x8*)(Bc + bBase + j * 1024 + koff1);
    }
    if (T + 1 < nt) STAGE_A(cn, 1, k0n);
    BAR();
    __builtin_amdgcn_s_setprio(1);
#pragma unroll
    for (int i = 0; i < 4; ++i)
#pragma unroll
      for (int j = 0; j < 2; ++j) {
        acc[i][j] = MFMA16(aR[i][0], bR[j][0], acc[i][j]);
        acc[i][j] = MFMA16(aR[i][1], bR[j][1], acc[i][j]);
      }
    __builtin_amdgcn_s_setprio(0);
    BAR();

    // ---- P2: read B j2-3; stage T+1 B-h0; compute Q1
#pragma unroll
    for (int j = 2; j < 4; ++j) {
      bR[j][0] = *(const bf16x8*)(Bc + bBase + j * 1024 + koff0);
      bR[j][1] = *(const bf16x8*)(Bc + bBase + j * 1024 + koff1);
    }
    if (T + 1 < nt) STAGE_B(cn, 0, k0n);
    BAR();
    __builtin_amdgcn_s_setprio(1);
#pragma unroll
    for (int i = 0; i < 4; ++i)
#pragma unroll
      for (int j = 2; j < 4; ++j) {
        acc[i][j] = MFMA16(aR[i][0], bR[j][0], acc[i][j]);
        acc[i][j] = MFMA16(aR[i][1], bR[j][1], acc[i][j]);
      }
    __builtin_amdgcn_s_setprio(0);
    BAR();

    // ---- P3: read A i4-7 (overwrite aR); stage T+1 B-h1; compute Q2
#pragma unroll
    for (int i = 0; i < 4; ++i) {
      aR[i][0] = *(const bf16x8*)(Ac + aBase + (i + 4) * 1024 + koff0);
      aR[i][1] = *(const bf16x8*)(Ac + aBase + (i + 4) * 1024 + koff1);
    }
    if (T + 1 < nt) STAGE_B(cn, 1, k0n);
    BAR();
    __builtin_amdgcn_s_setprio(1);
#pragma unroll
    for (int i = 0; i < 4; ++i)
#pragma unroll
      for (int j = 0; j < 2; ++j) {
        acc[i + 4][j] = MFMA16(aR[i][0], bR[j][0], acc[i + 4][j]);
        acc[i + 4][j] = MFMA16(aR[i][1], bR[j][1], acc[i + 4][j]);
      }
    __builtin_amdgcn_s_setprio(0);
    BAR();

    // ---- P4: stage T+2 A-h0 into freed buf c; compute Q3; counted vmcnt
    if (T + 2 < nt) STAGE_A(c, 0, (T + 2) << 6);
    __builtin_amdgcn_s_setprio(1);
#pragma unroll
    for (int i = 0; i < 4; ++i)
#pragma unroll
      for (int j = 2; j < 4; ++j) {
        acc[i + 4][j] = MFMA16(aR[i][0], bR[j][0], acc[i + 4][j]);
        acc[i + 4][j] = MFMA16(aR[i][1], bR[j][1], acc[i + 4][j]);
      }
    __builtin_amdgcn_s_setprio(0);
    if (T + 2 < nt) { asm volatile("s_waitcnt vmcnt(2)" ::: "memory"); }
    else            { asm volatile("s_waitcnt vmcnt(0)" ::: "memory"); }
    BAR();
  }

  // ---- epilogue: C/D layout col=lane&15, row=(lane>>4)*4+reg
  const int rbase = brow * 256 + wm * 128 + (lane >> 4) * 4;
  const int cbase = bcol * 256 + wn * 64 + lr;
#pragma unroll
  for (int i = 0; i < 8; ++i)
#pragma unroll
    for (int j = 0; j < 4; ++j)
#pragma unroll
      for (int q = 0; q < 4; ++q)
        C[(size_t)(rbase + i * 16 + q) * N + cbase + j * 16] = f2bf(acc[i][j][q]);
}

// ---------- prep kernels ----------
__global__ void prep_x_kernel(const float* __restrict__ x, const float* __restrict__ h,
                              unsigned short* __restrict__ Xcat) {
  const int total4 = BATCH * 2048 / 4;
  for (int i = blockIdx.x * blockDim.x + threadIdx.x; i < total4; i += gridDim.x * blockDim.x) {
    const int e = i * 4;
    const int m = e >> 11;
    const int c = e & 2047;
    float4 v = (c < 1024) ? *(const float4*)(x + (size_t)m * 1024 + c)
                          : *(const float4*)(h + (size_t)m * 1024 + (c - 1024));
    ushort4 o;
    o.x = f2bf(v.x); o.y = f2bf(v.y); o.z = f2bf(v.z); o.w = f2bf(v.w);
    *(ushort4*)(Xcat + e) = o;
  }
}

__global__ void prep_wcat_kernel(const float* __restrict__ Wz, const float* __restrict__ Uz,
                                 const float* __restrict__ Wr, const float* __restrict__ Ur,
                                 unsigned short* __restrict__ Wcat) {
  const int total4 = 2048 * 2048 / 4;
  for (int i = blockIdx.x * blockDim.x + threadIdx.x; i < total4; i += gridDim.x * blockDim.x) {
    const int e = i * 4;
    const int n = e >> 11;
    const int c = e & 2047;
    const float* src;
    if (n < 1024) src = (c < 1024) ? (Wz + (size_t)n * 1024 + c) : (Uz + (size_t)n * 1024 + c - 1024);
    else          src = (c < 1024) ? (Wr + (size_t)(n - 1024) * 1024 + c) : (Ur + (size_t)(n - 1024) * 1024 + c - 1024);
    float4 v = *(const float4*)src;
    ushort4 o;
    o.x = f2bf(v.x); o.y = f2bf(v.y); o.z = f2bf(v.z); o.w = f2bf(v.w);
    *(ushort4*)(Wcat + e) = o;
  }
}

__global__ void cast_f2b_kernel(const float* __restrict__ src, unsigned short* __restrict__ dst,
                                int total4) {
  for (int i = blockIdx.x * blockDim.x + threadIdx.x; i < total4; i += gridDim.x * blockDim.x) {
    const int e = i * 4;
    float4 v = *(const float4*)(src + e);
    ushort4 o;
    o.x = f2bf(v.x); o.y = f2bf(v.y); o.z = f2bf(v.z); o.w = f2bf(v.w);
    *(ushort4*)(dst + e) = o;
  }
}

__global__ void prep_A_kernel(const float* __restrict__ Wh, unsigned short* __restrict__ Abf) {
  const int total4 = 1024 * 1024 / 4;
  for (int i = blockIdx.x * blockDim.x + threadIdx.x; i < total4; i += gridDim.x * blockDim.x) {
    const int e = i * 4;
    const int r = e >> 10;
    const int c = e & 1023;
    float4 v = *(const float4*)(Wh + (size_t)r * 1024 + c);
    float t0 = Wh[(size_t)(c + 0) * 1024 + r];
    float t1 = Wh[(size_t)(c + 1) * 1024 + r];
    float t2 = Wh[(size_t)(c + 2) * 1024 + r];
    float t3 = Wh[(size_t)(c + 3) * 1024 + r];
    ushort4 o;
    o.x = f2bf(v.x - t0 - ((r == c + 0) ? GAMMA : 0.0f));
    o.y = f2bf(v.y - t1 - ((r == c + 1) ? GAMMA : 0.0f));
    o.z = f2bf(v.z - t2 - ((r == c + 2) ? GAMMA : 0.0f));
    o.w = f2bf(v.w - t3 - ((r == c + 3) ? GAMMA : 0.0f));
    *(ushort4*)(Abf + e) = o;
  }
}

__global__ void phase3_kernel(const unsigned short* __restrict__ ZR, const float* __restrict__ br,
                              const float* __restrict__ h, unsigned short* __restrict__ hr) {
  const int total4 = BATCH * 1024 / 4;
  for (int i = blockIdx.x * blockDim.x + threadIdx.x; i < total4; i += gridDim.x * blockDim.x) {
    const int e = i * 4;
    const int m = e >> 10;
    const int n = e & 1023;
    ushort4 rp = *(const ushort4*)(ZR + (size_t)m * 2048 + 1024 + n);
    float4 b  = *(const float4*)(br + n);
    float4 hv = *(const float4*)(h + e);
    ushort4 o;
    o.x = f2bf(sigmoidf_(bf2f(rp.x) + b.x) * hv.x);
    o.y = f2bf(sigmoidf_(bf2f(rp.y) + b.y) * hv.y);
    o.z = f2bf(sigmoidf_(bf2f(rp.z) + b.z) * hv.z);
    o.w = f2bf(sigmoidf_(bf2f(rp.w) + b.w) * hv.w);
    *(ushort4*)(hr + e) = o;
  }
}

__global__ void phase5_kernel(const unsigned short* __restrict__ ZR,
                              const unsigned short* __restrict__ Vpre,
                              const unsigned short* __restrict__ hA,
                              const float* __restrict__ bz, const float* __restrict__ bh,
                              const float* __restrict__ h, const float* __restrict__ eps_p,
                              float* __restrict__ out) {
  const float eps = eps_p[0];
  const int total4 = BATCH * 1024 / 4;
  for (int i = blockIdx.x * blockDim.x + threadIdx.x; i < total4; i += gridDim.x * blockDim.x) {
    const int e = i * 4;
    const int m = e >> 10;
    const int n = e & 1023;
    ushort4 zp = *(const ushort4*)(ZR + (size_t)m * 2048 + n);
    ushort4 vp = *(const ushort4*)(Vpre + e);
    ushort4 ha = *(const ushort4*)(hA + e);
    float4 bzv = *(const float4*)(bz + n);
    float4 bhv = *(const float4*)(bh + n);
    float4 hv  = *(const float4*)(h + e);
    float4 o;
    o.x = hv.x + eps * sigmoidf_(bf2f(zp.x) + bzv.x) * tanhf_(bf2f(vp.x) + bhv.x + bf2f(ha.x));
    o.y = hv.y + eps * sigmoidf_(bf2f(zp.y) + bzv.y) * tanhf_(bf2f(vp.y) + bhv.y + bf2f(ha.y));
    o.z = hv.z + eps * sigmoidf_(bf2f(zp.z) + bzv.z) * tanhf_(bf2f(vp.z) + bhv.z + bf2f(ha.z));
    o.w = hv.w + eps * sigmoidf_(bf2f(zp.w) + bzv.w) * tanhf_(bf2f(vp.w) + bhv.w + bf2f(ha.w));
    *(float4*)(out + e) = o;
  }
}

// ---------- launch ----------
extern "C" void kernel_launch(void* const* d_in, const int* in_sizes, int n_in,
                              void* d_out, int out_size, void* d_ws, size_t ws_size,
                              hipStream_t stream) {
  const float* x   = (const float*)d_in[0];
  const float* h   = (const float*)d_in[1];
  const float* Wz  = (const float*)d_in[2];
  const float* bz  = (const float*)d_in[3];
  const float* Uz  = (const float*)d_in[4];
  const float* Wr  = (const float*)d_in[5];
  const float* br  = (const float*)d_in[6];
  const float* Ur  = (const float*)d_in[7];
  const float* Vh  = (const float*)d_in[8];
  const float* bh  = (const float*)d_in[9];
  const float* Wh  = (const float*)d_in[10];
  const float* eps = (const float*)d_in[11];
  float* out = (float*)d_out;

  char* ws = (char*)d_ws;
  size_t off = 0;
  unsigned short* Xcat = (unsigned short*)(ws + off); off += (size_t)BATCH * 2048 * 2;
  unsigned short* Wcat = (unsigned short*)(ws + off); off += (size_t)2048 * 2048 * 2;
  unsigned short* Vhb  = (unsigned short*)(ws + off); off += (size_t)1024 * 1024 * 2;
  unsigned short* Abf  = (unsigned short*)(ws + off); off += (size_t)1024 * 1024 * 2;
  unsigned short* ZR   = (unsigned short*)(ws + off); off += (size_t)BATCH * 2048 * 2;
  unsigned short* Vpre = (unsigned short*)(ws + off); off += (size_t)BATCH * 1024 * 2;
  unsigned short* hr = Xcat;                       // Xcat dead after GEMM2
  unsigned short* hA = Xcat + (size_t)BATCH * 1024;

  dim3 blk(256);
  prep_x_kernel<<<2048, blk, 0, stream>>>(x, h, Xcat);
  prep_wcat_kernel<<<1024, blk, 0, stream>>>(Wz, Uz, Wr, Ur, Wcat);
  cast_f2b_kernel<<<256, blk, 0, stream>>>(Vh, Vhb, 1024 * 1024 / 4);
  prep_A_kernel<<<256, blk, 0, stream>>>(Wh, Abf);

  dim3 gblk(512);
  // GEMM1: ZR = Xcat @ Wcat^T   (M=16384, N=2048, K=2048)
  gemm256<<<(BATCH / 256) * (2048 / 256), gblk, 0, stream>>>(Xcat, Wcat, ZR, 2048, 2048, 2048);
  // GEMM2: Vpre = x @ Vh^T      (x = first 1024 cols of Xcat, lda=2048)
  gemm256<<<(BATCH / 256) * (1024 / 256), gblk, 0, stream>>>(Xcat, Vhb, Vpre, 2048, 1024, 1024);
  phase3_kernel<<<2048, blk, 0, stream>>>(ZR, br, h, hr);
  // GEMM3: hA = hr @ A^T
  gemm256<<<(BATCH / 256) * (1024 / 256), gblk, 0, stream>>>(hr, Abf, hA, 1024, 1024, 1024);
  phase5_kernel<<<2048, blk, 0, stream>>>(ZR, Vpre, hA, bz, bh, h, eps, out);
}